// Round 3
// 5985.154 us; speedup vs baseline: 1.5872x; 1.5872x over previous
//
#include <hip/hip_runtime.h>

#define T_TOK 4096
#define HID   2048
#define NH    32
#define HD    128
#define PP    4096

typedef unsigned short u16;
typedef unsigned int   u32;
typedef __attribute__((ext_vector_type(8))) short short8;
typedef __attribute__((ext_vector_type(4))) float floatx4;
typedef __attribute__((ext_vector_type(2))) unsigned int uint2v;

__device__ __forceinline__ float b2f(u16 u) {
  union { u32 i; float f; } x; x.i = ((u32)u) << 16; return x.f;
}
__device__ __forceinline__ u16 f2b(float f) {
  u32 x = __float_as_uint(f);
  u32 r = (x + 0x7fffu + ((x >> 16) & 1u)) >> 16;
  return (u16)r;
}
__device__ __forceinline__ float blo(u32 u) { return __uint_as_float(u << 16); }
__device__ __forceinline__ float bhi(u32 u) { return __uint_as_float(u & 0xffff0000u); }

// fast transcendentals: v_exp_f32 / v_rcp_f32 (~1ulp fp32 — far below bf16 noise)
__device__ __forceinline__ float fexp(float x) {
  return __builtin_amdgcn_exp2f(x * 1.4426950408889634f);
}
__device__ __forceinline__ float fsig(float x) {
  return __builtin_amdgcn_rcpf(1.f + fexp(-x));
}

// 64-lane sum, broadcast to all lanes. 4x DPP row_ror within 16-lane rows,
// ds_swizzle xor16 within 32-halves, permlane32_swap across halves.
__device__ __forceinline__ float wsum64(float x) {
  int t;
  t = __builtin_amdgcn_update_dpp(0, __float_as_int(x), 0x121, 0xf, 0xf, true);
  x += __int_as_float(t);
  t = __builtin_amdgcn_update_dpp(0, __float_as_int(x), 0x122, 0xf, 0xf, true);
  x += __int_as_float(t);
  t = __builtin_amdgcn_update_dpp(0, __float_as_int(x), 0x124, 0xf, 0xf, true);
  x += __int_as_float(t);
  t = __builtin_amdgcn_update_dpp(0, __float_as_int(x), 0x128, 0xf, 0xf, true);
  x += __int_as_float(t);
  t = __builtin_amdgcn_ds_swizzle(__float_as_int(x), 0x401F); // lane ^ 16
  x += __int_as_float(t);
  uint2v p = __builtin_amdgcn_permlane32_swap(__float_as_uint(x), __float_as_uint(x), false, false);
  return __uint_as_float(p[0]) + __uint_as_float(p[1]);
}

// ---------------- GEMM: C[M,N]bf16 = A[M,K] * B[K,N]f32 via bf16 MFMA ----------------
template<int ABF16, int ASPL, int BSPL>
__global__ __launch_bounds__(256)
void gemm_k(const void* __restrict__ Av, const float* __restrict__ B,
            u16* __restrict__ C, int M, int N, int K) {
  __shared__ u16 As[ASPL + 1][64][40];
  __shared__ u16 Bs[BSPL + 1][32][72];
  const int tid  = threadIdx.x;
  const int lane = tid & 63;
  const int wave = tid >> 6;
  const long bm = (long)blockIdx.y * 64;
  const long bn = (long)blockIdx.x * 64;
  const int wm = (wave >> 1) * 32;
  const int wn = (wave & 1) * 32;
  const int ar = tid >> 2, ac = (tid & 3) * 8;
  const int br = tid >> 3, bc = (tid & 7) * 8;
  const int q = lane >> 4, r = lane & 15;
  floatx4 acc[2][2];
#pragma unroll
  for (int i = 0; i < 2; ++i)
#pragma unroll
    for (int j = 0; j < 2; ++j) acc[i][j] = (floatx4)0.f;

  for (int k0 = 0; k0 < K; k0 += 32) {
    u16 ahi[8], alo[8], bhi8[8], blo8[8];
    if (ABF16) {
      const u16* A = (const u16*)Av;
      *(float4*)ahi = *(const float4*)(A + (bm + ar) * (long)K + k0 + ac);
    } else {
      const float* A = (const float*)Av;
      const float* ap = A + (bm + ar) * (long)K + k0 + ac;
#pragma unroll
      for (int e = 0; e < 8; ++e) {
        float x = ap[e];
        u16 hh = f2b(x);
        ahi[e] = hh;
        if (ASPL) alo[e] = f2b(x - b2f(hh));
      }
    }
    {
      const float* bp = B + (long)(k0 + br) * N + bn + bc;
#pragma unroll
      for (int e = 0; e < 8; ++e) {
        float x = bp[e];
        u16 hh = f2b(x);
        bhi8[e] = hh;
        if (BSPL) blo8[e] = f2b(x - b2f(hh));
      }
    }
    __syncthreads();
    *(float4*)&As[0][ar][ac] = *(float4*)ahi;
    *(float4*)&Bs[0][br][bc] = *(float4*)bhi8;
    if (ASPL) *(float4*)&As[ASPL][ar][ac] = *(float4*)alo;
    if (BSPL) *(float4*)&Bs[BSPL][br][bc] = *(float4*)blo8;
    __syncthreads();
    short8 afh[2], afl[2], bfh[2], bfl[2];
#pragma unroll
    for (int i = 0; i < 2; ++i) {
      afh[i] = *(const short8*)&As[0][wm + i * 16 + r][q * 8];
      if (ASPL) afl[i] = *(const short8*)&As[ASPL][wm + i * 16 + r][q * 8];
    }
#pragma unroll
    for (int i = 0; i < 2; ++i) {
      short8 th, tl;
#pragma unroll
      for (int j = 0; j < 8; ++j) {
        th[j] = (short)Bs[0][q * 8 + j][wn + i * 16 + r];
        if (BSPL) tl[j] = (short)Bs[BSPL][q * 8 + j][wn + i * 16 + r];
      }
      bfh[i] = th;
      if (BSPL) bfl[i] = tl;
    }
#pragma unroll
    for (int i = 0; i < 2; ++i)
#pragma unroll
      for (int j = 0; j < 2; ++j) {
        acc[i][j] = __builtin_amdgcn_mfma_f32_16x16x32_bf16(afh[i], bfh[j], acc[i][j], 0, 0, 0);
        if (BSPL) acc[i][j] = __builtin_amdgcn_mfma_f32_16x16x32_bf16(afh[i], bfl[j], acc[i][j], 0, 0, 0);
        if (ASPL) acc[i][j] = __builtin_amdgcn_mfma_f32_16x16x32_bf16(afl[i], bfh[j], acc[i][j], 0, 0, 0);
      }
  }
#pragma unroll
  for (int i = 0; i < 2; ++i)
#pragma unroll
    for (int j = 0; j < 2; ++j) {
      long col = bn + wn + j * 16 + r;
#pragma unroll
      for (int e = 0; e < 4; ++e) {
        long row = bm + wm + i * 16 + q * 4 + e;
        C[row * N + col] = f2b(acc[i][j][e]);
      }
    }
}

// ---------------- beta = 2*sigmoid(hs @ Wb)  [T,32] f32 ----------------
__global__ __launch_bounds__(256)
void beta_k(const float* __restrict__ hs, const float* __restrict__ Wb, float* __restrict__ beta) {
  int t = blockIdx.x * 8 + (threadIdx.x >> 5);
  int h = threadIdx.x & 31;
  const float* hrow = hs + (long)t * HID;
  float acc = 0.f;
  for (int k = 0; k < HID; ++k)
    acc += hrow[k] * Wb[k * NH + h];
  beta[t * NH + h] = 2.f * fsig(acc);
}

// ---- x = -5*sigmoid(exp(A_log[h]) * (g1pre + dt_bias)) in place bf16 (log-domain) ----
__global__ __launch_bounds__(256)
void expg_k(u16* __restrict__ g1, const float* __restrict__ dtb, const float* __restrict__ Alog) {
  int idx = blockIdx.x * 256 + threadIdx.x;
  int p = idx & (PP - 1);
  int h = p >> 7;
  float g = b2f(g1[idx]) + dtb[p];
  float a = fexp(Alog[h]);
  g1[idx] = f2b(-5.f * fsig(a * g));
}

// ---------------- fused conv+silu + gated delta-rule scan ----------------
// Round-0 dataflow (numerics-critical): q/k/v causal conv(K=4)+SiLU computed
// IN-SCAN in fp32 from raw bf16 projections — no extra bf16 round-trip anywhere
// on the state/output path (rounds 1-2 failed accuracy from prepass rounding).
// Only scheduling-level changes vs round 0: v_exp/v_rcp transcendentals and
// DPP-based wsum64. One wave per (head, v-column); lane owns k-channels
// {2*lane, 2*lane+1}. o overwrites v in place.
__global__ __launch_bounds__(256)
void scan_k(const u16* __restrict__ preq, const u16* __restrict__ prek,
            u16* __restrict__ prev, const u16* __restrict__ gx,
            const float* __restrict__ beta,
            const float* __restrict__ cqw, const float* __restrict__ ckw,
            const float* __restrict__ cvw) {
  int wid  = blockIdx.x * 4 + (threadIdx.x >> 6);  // h*128 + vc
  int lane = threadIdx.x & 63;
  int h = wid >> 7, vc = wid & 127;
  int c0  = h * HD + 2 * lane;   // q/k channel pair
  int cv0 = h * HD + vc;         // v channel (wave-uniform)
  float qw[4][2], kw[4][2], vw[4];
#pragma unroll
  for (int j = 0; j < 4; ++j) {
    qw[j][0] = cqw[c0 * 4 + j];       qw[j][1] = cqw[(c0 + 1) * 4 + j];
    kw[j][0] = ckw[c0 * 4 + j];       kw[j][1] = ckw[(c0 + 1) * 4 + j];
    vw[j]    = cvw[cv0 * 4 + j];
  }
  const u32* q32 = (const u32*)preq;
  const u32* k32 = (const u32*)prek;
  const u32* x32 = (const u32*)gx;
  float hq0x = 0.f, hq0y = 0.f, hq1x = 0.f, hq1y = 0.f, hq2x = 0.f, hq2y = 0.f;
  float hk0x = 0.f, hk0y = 0.f, hk1x = 0.f, hk1y = 0.f, hk2x = 0.f, hk2y = 0.f;
  float hv0 = 0.f, hv1 = 0.f, hv2 = 0.f;
  float Sx = 0.f, Sy = 0.f;
  const float qscale = 0.08838834764831845f;  // HD^-0.5
#pragma unroll 4
  for (int t = 0; t < T_TOK; ++t) {
    int rb = t * (PP / 2) + h * 64 + lane;
    u32 qr = q32[rb], kr = k32[rb], xr = x32[rb];
    float vraw = b2f(prev[t * PP + cv0]);
    float bt = beta[t * NH + h];
    float qx = blo(qr), qy = bhi(qr);
    float kx = blo(kr), ky = bhi(kr);
    // causal conv (w[3]*x[t] + w[2]*x[t-1] + w[1]*x[t-2] + w[0]*x[t-3]), fp32
    float cq0 = qw[3][0] * qx + qw[2][0] * hq0x + qw[1][0] * hq1x + qw[0][0] * hq2x;
    float cq1 = qw[3][1] * qy + qw[2][1] * hq0y + qw[1][1] * hq1y + qw[0][1] * hq2y;
    float ck0 = kw[3][0] * kx + kw[2][0] * hk0x + kw[1][0] * hk1x + kw[0][0] * hk2x;
    float ck1 = kw[3][1] * ky + kw[2][1] * hk0y + kw[1][1] * hk1y + kw[0][1] * hk2y;
    float cvv = vw[3] * vraw + vw[2] * hv0 + vw[1] * hv1 + vw[0] * hv2;
    hq2x = hq1x; hq1x = hq0x; hq0x = qx;
    hq2y = hq1y; hq1y = hq0y; hq0y = qy;
    hk2x = hk1x; hk1x = hk0x; hk0x = kx;
    hk2y = hk1y; hk1y = hk0y; hk0y = ky;
    hv2 = hv1; hv1 = hv0; hv0 = vraw;
    float qv0 = cq0 * fsig(cq0) * qscale;
    float qv1 = cq1 * fsig(cq1) * qscale;
    float kv0 = ck0 * fsig(ck0);
    float kv1 = ck1 * fsig(ck1);
    float vv  = cvv * fsig(cvv);
    // recurrence
    Sx *= fexp(blo(xr)); Sy *= fexp(bhi(xr));
    float pr = wsum64(fmaf(kv0, Sx, kv1 * Sy));
    float u = bt * (vv - pr);
    Sx = fmaf(kv0, u, Sx);
    Sy = fmaf(kv1, u, Sy);
    float o = wsum64(fmaf(qv0, Sx, qv1 * Sy));
    if (lane == 0) prev[t * PP + cv0] = f2b(o);
  }
}

// ---------------- rinv[t,h] = rsqrt(mean(o^2) + eps) ----------------
__global__ __launch_bounds__(256)
void rms_k(const u16* __restrict__ ob, float* __restrict__ rinv) {
  int wid  = blockIdx.x * 4 + (threadIdx.x >> 6);  // t*32 + h
  int lane = threadIdx.x & 63;
  u32 o2 = ((const u32*)ob)[(long)wid * 64 + lane];
  float ox = blo(o2), oy = bhi(o2);
  float ss = wsum64(ox * ox + oy * oy);
  if (lane == 0) rinv[wid] = rsqrtf(ss * (1.f / 128.f) + 1e-5f);
}

// ---------------- final GEMM with fused gated-RMSNorm A-staging ----------------
__global__ __launch_bounds__(256)
void gemm_final_k(const u16* __restrict__ ob, const u16* __restrict__ g2,
                  const float* __restrict__ rinv, const float* __restrict__ wn,
                  const float* __restrict__ Wo, float* __restrict__ C) {
  __shared__ u16 As[2][64][40];
  __shared__ u16 Bs[2][32][72];
  const int tid  = threadIdx.x;
  const int lane = tid & 63;
  const int wave = tid >> 6;
  const long bm = (long)blockIdx.y * 64;
  const long bn = (long)blockIdx.x * 64;
  const int wm = (wave >> 1) * 32;
  const int wn_ = (wave & 1) * 32;
  const int ar = tid >> 2, ac = (tid & 3) * 8;
  const int br = tid >> 3, bc = (tid & 7) * 8;
  const int q = lane >> 4, r = lane & 15;
  const int N = HID, K = PP;
  floatx4 acc[2][2];
#pragma unroll
  for (int i = 0; i < 2; ++i)
#pragma unroll
    for (int j = 0; j < 2; ++j) acc[i][j] = (floatx4)0.f;

  for (int k0 = 0; k0 < K; k0 += 32) {
    u16 ahi[8], alo[8], bhi8[8], blo8[8];
    {
      long t = bm + ar;
      int c = k0 + ac;
      float ri = rinv[t * NH + (c >> 7)];
      const u16* op = ob + t * PP + c;
      const u16* gp = g2 + t * PP + c;
#pragma unroll
      for (int e = 0; e < 8; ++e) {
        float a = b2f(op[e]) * ri * wn[(c & 127) + e] * fsig(b2f(gp[e]));
        u16 hh = f2b(a);
        ahi[e] = hh;
        alo[e] = f2b(a - b2f(hh));
      }
      const float* bp = Wo + (long)(k0 + br) * N + bn + bc;
#pragma unroll
      for (int e = 0; e < 8; ++e) {
        float x = bp[e];
        u16 hh = f2b(x);
        bhi8[e] = hh;
        blo8[e] = f2b(x - b2f(hh));
      }
    }
    __syncthreads();
    *(float4*)&As[0][ar][ac] = *(float4*)ahi;
    *(float4*)&As[1][ar][ac] = *(float4*)alo;
    *(float4*)&Bs[0][br][bc] = *(float4*)bhi8;
    *(float4*)&Bs[1][br][bc] = *(float4*)blo8;
    __syncthreads();
    short8 afh[2], afl[2], bfh[2], bfl[2];
#pragma unroll
    for (int i = 0; i < 2; ++i) {
      afh[i] = *(const short8*)&As[0][wm + i * 16 + r][q * 8];
      afl[i] = *(const short8*)&As[1][wm + i * 16 + r][q * 8];
    }
#pragma unroll
    for (int i = 0; i < 2; ++i) {
      short8 th, tl;
#pragma unroll
      for (int j = 0; j < 8; ++j) {
        th[j] = (short)Bs[0][q * 8 + j][wn_ + i * 16 + r];
        tl[j] = (short)Bs[1][q * 8 + j][wn_ + i * 16 + r];
      }
      bfh[i] = th; bfl[i] = tl;
    }
#pragma unroll
    for (int i = 0; i < 2; ++i)
#pragma unroll
      for (int j = 0; j < 2; ++j) {
        acc[i][j] = __builtin_amdgcn_mfma_f32_16x16x32_bf16(afh[i], bfh[j], acc[i][j], 0, 0, 0);
        acc[i][j] = __builtin_amdgcn_mfma_f32_16x16x32_bf16(afh[i], bfl[j], acc[i][j], 0, 0, 0);
        acc[i][j] = __builtin_amdgcn_mfma_f32_16x16x32_bf16(afl[i], bfh[j], acc[i][j], 0, 0, 0);
      }
  }
#pragma unroll
  for (int i = 0; i < 2; ++i)
#pragma unroll
    for (int j = 0; j < 2; ++j) {
      long col = bn + wn_ + j * 16 + r;
#pragma unroll
      for (int e = 0; e < 4; ++e) {
        long row = bm + wm + i * 16 + q * 4 + e;
        C[row * N + col] = acc[i][j][e];
      }
    }
}

extern "C" void kernel_launch(void* const* d_in, const int* in_sizes, int n_in,
                              void* d_out, int out_size, void* d_ws, size_t ws_size,
                              hipStream_t stream) {
  const float* hs   = (const float*)d_in[0];
  const float* Wq   = (const float*)d_in[1];
  const float* Wk   = (const float*)d_in[2];
  const float* Wv   = (const float*)d_in[3];
  const float* cq   = (const float*)d_in[4];
  const float* ck   = (const float*)d_in[5];
  const float* cv   = (const float*)d_in[6];
  const float* Wb   = (const float*)d_in[7];
  const float* Wfa  = (const float*)d_in[8];
  const float* Wfb  = (const float*)d_in[9];
  const float* dtb  = (const float*)d_in[10];
  const float* Alog = (const float*)d_in[11];
  const float* Wga  = (const float*)d_in[12];
  const float* Wgb  = (const float*)d_in[13];
  const float* wn   = (const float*)d_in[14];
  const float* Wo   = (const float*)d_in[15];

  char* ws = (char*)d_ws;
  const size_t SZB = (size_t)T_TOK * PP * 2;     // 32 MiB per bf16 [T,P]
  u16*   B0   = (u16*)(ws + 0 * SZB);            // pre_q raw
  u16*   B1   = (u16*)(ws + 1 * SZB);            // pre_k raw; after scan: g2pre
  u16*   B2   = (u16*)(ws + 2 * SZB);            // pre_v raw -> o (in-place)
  u16*   B3   = (u16*)(ws + 3 * SZB);            // g1pre -> log-domain decay x
  float* beta = (float*)(ws + 4 * SZB);                      // 512 KiB
  float* rinv = (float*)(ws + 4 * SZB + (512u << 10));       // 512 KiB
  u16*   hfa  = (u16*)(ws + 4 * SZB + (1u << 20));           // [T,128] bf16, 1 MiB
  u16*   hga  = (u16*)(ws + 4 * SZB + (2u << 20));           // [T,128] bf16, 1 MiB
  // total extent: 128 MiB + 3 MiB (identical to round 0, which ran)

  dim3 blk(256);
  dim3 g_big(PP / 64, T_TOK / 64);
  dim3 g_thin(HD / 64, T_TOK / 64);
  const int EW = T_TOK * PP / 256;

  // raw projections (split = fp32-quality), stored bf16
  gemm_k<0, 1, 1><<<g_big, blk, 0, stream>>>(hs, Wq, B0, T_TOK, PP, HID);
  gemm_k<0, 1, 1><<<g_big, blk, 0, stream>>>(hs, Wk, B1, T_TOK, PP, HID);
  gemm_k<0, 1, 1><<<g_big, blk, 0, stream>>>(hs, Wv, B2, T_TOK, PP, HID);
  // beta (fp32 scalar dot)
  beta_k<<<T_TOK / 8, blk, 0, stream>>>(hs, Wb, beta);
  // g1 path -> log-domain decay x in B3
  gemm_k<0, 1, 1><<<g_thin, blk, 0, stream>>>(hs, Wfa, hfa, T_TOK, HD, HID);
  gemm_k<1, 0, 1><<<g_big, blk, 0, stream>>>(hfa, Wfb, B3, T_TOK, PP, HD);
  expg_k<<<EW, blk, 0, stream>>>(B3, dtb, Alog);
  // g2 first stage
  gemm_k<0, 1, 1><<<g_thin, blk, 0, stream>>>(hs, Wga, hga, T_TOK, HD, HID);
  // fused conv+silu+scan (o -> B2 in place)
  scan_k<<<T_TOK / 4, blk, 0, stream>>>(B0, B1, B2, B3, beta, cq, ck, cv);
  // g2 second stage into freed B1
  gemm_k<1, 0, 1><<<g_big, blk, 0, stream>>>(hga, Wgb, B1, T_TOK, PP, HD);
  // rms factors
  rms_k<<<T_TOK * NH / 4, blk, 0, stream>>>(B2, rinv);
  // final projection with fused gated RMSNorm, fp32 out
  gemm_final_k<<<dim3(HID / 64, T_TOK / 64), blk, 0, stream>>>(B2, B1, rinv, wn, Wo, (float*)d_out);
}